// Round 5
// baseline (8036.317 us; speedup 1.0000x reference)
//
#include <hip/hip_runtime.h>
#include <stdint.h>

// ---------------------------------------------------------------------------
// Fused SDE sampler, round 5.
//   Diagnosis r3/r4: 8-wave blocks forced 4 waves/EU -> unified-file cap 128
//   = 64 arch + 64 acc -> ~50 spilled arch regs re-read every step (FETCH
//   14.5 GB, VALUBusy 60% of mostly spill code).
//   Fix: 256-thread blocks (4 waves), 32 rows/block, waves_per_eu(3,4)
//   -> 170-reg cap (~106 arch + 64 acc), LDS 40.8 KB -> 3 blocks/CU
//   (12 waves, 37.5% occ), zero spills.
//   Kept from r3/r4: swapped MFMA operands (A=weights -> b64/b128 epilogue
//   writes), c0 = x0@W1[64:128] hoisted into persistent AGPRs, biases in
//   LDS, f32 drift overlay, bit-exact JAX threefry RNG (verified r1-r4).
// ---------------------------------------------------------------------------

#define PARTITIONABLE 1

namespace {

constexpr int   kObs    = 65536;
constexpr int   kDim    = 64;
constexpr int   kSteps  = 64;
constexpr float kDs     = 1.0f / 64.0f;
constexpr float kSqrtDs = 0.125f;

typedef _Float16 f16x8 __attribute__((ext_vector_type(8)));
typedef _Float16 f16x4 __attribute__((ext_vector_type(4)));
typedef float    f32x4 __attribute__((ext_vector_type(4)));

#define MFMA16(a, b, c) __builtin_amdgcn_mfma_f32_16x16x32_f16((a), (b), (c), 0, 0, 0)

__device__ __forceinline__ uint32_t rotl(uint32_t v, int r) {
  return (v << r) | (v >> (32 - r));
}

__device__ __forceinline__ void tf2x32(uint32_t k0, uint32_t k1,
                                       uint32_t& x0, uint32_t& x1) {
  uint32_t k2 = k0 ^ k1 ^ 0x1BD11BDAu;
  x0 += k0; x1 += k1;
  x0 += x1; x1 = rotl(x1, 13); x1 ^= x0;
  x0 += x1; x1 = rotl(x1, 15); x1 ^= x0;
  x0 += x1; x1 = rotl(x1, 26); x1 ^= x0;
  x0 += x1; x1 = rotl(x1,  6); x1 ^= x0;
  x0 += k1; x1 += k2 + 1u;
  x0 += x1; x1 = rotl(x1, 17); x1 ^= x0;
  x0 += x1; x1 = rotl(x1, 29); x1 ^= x0;
  x0 += x1; x1 = rotl(x1, 16); x1 ^= x0;
  x0 += x1; x1 = rotl(x1, 24); x1 ^= x0;
  x0 += k2; x1 += k0 + 2u;
  x0 += x1; x1 = rotl(x1, 13); x1 ^= x0;
  x0 += x1; x1 = rotl(x1, 15); x1 ^= x0;
  x0 += x1; x1 = rotl(x1, 26); x1 ^= x0;
  x0 += x1; x1 = rotl(x1,  6); x1 ^= x0;
  x0 += k0; x1 += k1 + 3u;
  x0 += x1; x1 = rotl(x1, 17); x1 ^= x0;
  x0 += x1; x1 = rotl(x1, 29); x1 ^= x0;
  x0 += x1; x1 = rotl(x1, 16); x1 ^= x0;
  x0 += x1; x1 = rotl(x1, 24); x1 ^= x0;
  x0 += k1; x1 += k2 + 4u;
  x0 += x1; x1 = rotl(x1, 13); x1 ^= x0;
  x0 += x1; x1 = rotl(x1, 15); x1 ^= x0;
  x0 += x1; x1 = rotl(x1, 26); x1 ^= x0;
  x0 += x1; x1 = rotl(x1,  6); x1 ^= x0;
  x0 += k2; x1 += k0 + 5u;
}

__device__ __forceinline__ void jax_split(uint32_t k0, uint32_t k1,
                                          uint32_t& a0, uint32_t& a1,
                                          uint32_t& b0, uint32_t& b1) {
#if PARTITIONABLE
  uint32_t x0 = 0u, x1 = 0u; tf2x32(k0, k1, x0, x1); a0 = x0; a1 = x1;
  uint32_t y0 = 0u, y1 = 1u; tf2x32(k0, k1, y0, y1); b0 = y0; b1 = y1;
#else
  uint32_t x0 = 0u, x1 = 2u; tf2x32(k0, k1, x0, x1);
  uint32_t y0 = 1u, y1 = 3u; tf2x32(k0, k1, y0, y1);
  a0 = x0; a1 = y0; b0 = x1; b1 = y1;
#endif
}

__device__ __forceinline__ uint32_t draw_bits(uint32_t k0, uint32_t k1, uint32_t i) {
#if PARTITIONABLE
  uint32_t x0 = 0u, x1 = i;
  tf2x32(k0, k1, x0, x1);
  return x0 ^ x1;
#else
  const uint32_t half = (uint32_t)kObs * kDim / 2;
  if (i < half) {
    uint32_t x0 = i, x1 = i + half; tf2x32(k0, k1, x0, x1); return x0;
  } else {
    uint32_t x0 = i - half, x1 = i; tf2x32(k0, k1, x0, x1); return x1;
  }
#endif
}

__device__ __forceinline__ float erfinv32(float x) {
  float w = -log1pf(-x * x);
  float p;
  if (w < 5.0f) {
    w = w - 2.5f;
    p =            2.81022636e-08f;
    p = fmaf(p, w, 3.43273939e-07f);
    p = fmaf(p, w, -3.5233877e-06f);
    p = fmaf(p, w, -4.39150654e-06f);
    p = fmaf(p, w, 0.00021858087f);
    p = fmaf(p, w, -0.00125372503f);
    p = fmaf(p, w, -0.00417768164f);
    p = fmaf(p, w, 0.246640727f);
    p = fmaf(p, w, 1.50140941f);
  } else {
    w = sqrtf(w) - 3.0f;
    p =            -0.000200214257f;
    p = fmaf(p, w, 0.000100950558f);
    p = fmaf(p, w, 0.00134934322f);
    p = fmaf(p, w, -0.00367342844f);
    p = fmaf(p, w, 0.00573950773f);
    p = fmaf(p, w, -0.0076224613f);
    p = fmaf(p, w, 0.00943887047f);
    p = fmaf(p, w, 1.00167406f);
    p = fmaf(p, w, 2.83297682f);
  }
  return p * x;
}

__device__ __forceinline__ float bits_to_normal(uint32_t bits) {
  const float lo = -0.99999994f;
  float f = __uint_as_float(0x3f800000u | (bits >> 9)) - 1.0f;
  float u = fmaxf(lo, fmaf(f, 2.0f, lo));
  return 1.41421356237f * erfinv32(u);
}

}  // namespace

// ---------------------------------------------------------------------------
// Weight prep (unchanged from r3/r4): fp32 -> f16 MFMA A-operand fragments.
// Tile = 16(M=neuron) x 32(K) = 1024 B; lane l holds A[m=l&15][k=(l>>4)*8+j].
//   L1: tiles [  0, 64): id =       Mt*4 + kt  (kt 0,1 = x rows; 2,3 = x0)
//   L2: tiles [ 64,192): id =  64 + Mt*8 + kt
//   L3: tiles [192,224): id = 192 + Mt*8 + kt  (Mt 0..3)
// ---------------------------------------------------------------------------
__global__ void prep_weights(const float* __restrict__ W1,
                             const float* __restrict__ W2,
                             const float* __restrict__ W3,
                             _Float16* __restrict__ ws) {
  const int tile = blockIdx.x;
  const int t    = threadIdx.x;
  const int lane = t >> 2;
  const int j0   = (t & 3) * 2;
  const int lm   = lane & 15;
  const int hi   = lane >> 4;

  int Mt, kt, ld;
  const float* src;
  if (tile < 64)       { Mt = tile >> 2;            kt = tile & 3; src = W1; ld = 256; }
  else if (tile < 192) { int u = tile - 64;  Mt = u >> 3; kt = u & 7; src = W2; ld = 256; }
  else                 { int u = tile - 192; Mt = u >> 3; kt = u & 7; src = W3; ld = 64;  }

  const int col = Mt * 16 + lm;
#pragma unroll
  for (int jj = 0; jj < 2; ++jj) {
    const int j = j0 + jj;
    const int k = kt * 32 + hi * 8 + j;
    ws[(size_t)tile * 512 + lane * 8 + j] = (_Float16)src[k * ld + col];
  }
}

// ---------------------------------------------------------------------------
// Main fused kernel: 32 rows/block, 256 threads (4 waves).
// Wave w owns M-tiles {4w..4w+3} (neurons 64w..64w+64) for L1/L2, both
// N-tiles; for L3 (M=64) wave w owns M-tile w, both N-tiles.
// ---------------------------------------------------------------------------
__global__ __launch_bounds__(256)
__attribute__((amdgpu_waves_per_eu(3, 4)))
void sde_mfma5(const float* __restrict__ X0g,
               const float* __restrict__ W1,
               const float* __restrict__ b1g,
               const float* __restrict__ b2g,
               const float* __restrict__ b3g,
               const _Float16* __restrict__ ws,
               float* __restrict__ out) {
  // LDS: 4608 + 16896 + 16896 + 3328 = 41728 B -> 3 blocks/CU.
  __shared__ alignas(16) _Float16 xB[32][72];    // X as f16, B-frag layout
  __shared__ alignas(16) _Float16 h1[32][264];
  __shared__ alignas(16) _Float16 h2[32][264];
  __shared__ alignas(16) float    sB[832];       // b1|w1s|b2|b3
  // f32 drift overlay on h1 (dead there by L3): 32*72*4 = 9216 <= 16896
  float (*drF)[72] = reinterpret_cast<float (*)[72]>(&h1[0][0]);

  const int t  = threadIdx.x;
  const int w  = t >> 6;                 // wave 0..3
  const int l  = t & 63;
  const int lq = l >> 4;                 // quad
  const int lm = l & 15;
  const int samp = blockIdx.x >> 11;     // 2048 blocks per sample chain
  const int tile = blockIdx.x & 2047;
  const int r0   = tile * 32;

  const int li = t >> 3;                 // update-phase row 0..31
  const int ci = (t & 7) * 8;            // update-phase col base

  // ---- init: X/X0 in registers, xB <- f16(X0), biases -> LDS ----
  float X[8], X0r[8];
  {
    const float* p = X0g + (size_t)(r0 + li) * kDim + ci;
    const float4 a = *(const float4*)p;
    const float4 b = *(const float4*)(p + 4);
    X0r[0] = a.x; X0r[1] = a.y; X0r[2] = a.z; X0r[3] = a.w;
    X0r[4] = b.x; X0r[5] = b.y; X0r[6] = b.z; X0r[7] = b.w;
    f16x8 hx;
#pragma unroll
    for (int j = 0; j < 8; ++j) { X[j] = X0r[j]; hx[j] = (_Float16)X0r[j]; }
    *(f16x8*)&xB[li][ci] = hx;
  }
  {
    sB[t]       = b1g[t];
    sB[256 + t] = W1[128 * 256 + t];
    sB[512 + t] = b2g[t];
    if (t < 64) sB[768 + t] = b3g[t];
  }

  // ---- RNG key chain ----
  uint32_t s0a, s0b, s1a, s1b;
  jax_split(0u, 1u, s0a, s0b, s1a, s1b);
  const uint32_t sk0 = samp ? s1a : s0a;
  const uint32_t sk1 = samp ? s1b : s0b;
  uint32_t kd0, kd1, kl0, kl1;
  jax_split(sk0, sk1, kd0, kd1, kl0, kl1);

  __syncthreads();

  // ---- c0[m][nt] = x0 @ W1[64:128]  (persistent AGPR C-init) ----
  f32x4 c0[4][2];
#pragma unroll
  for (int m = 0; m < 4; ++m)
#pragma unroll
    for (int nt = 0; nt < 2; ++nt) c0[m][nt] = (f32x4){0.f, 0.f, 0.f, 0.f};
#pragma unroll
  for (int kt2 = 0; kt2 < 2; ++kt2) {
    f16x8 bf[2];
#pragma unroll
    for (int nt = 0; nt < 2; ++nt)
      bf[nt] = *(const f16x8*)&xB[16 * nt + lm][kt2 * 32 + lq * 8];  // xB==x0
#pragma unroll
    for (int m = 0; m < 4; ++m) {
      const f16x8 af =
          *(const f16x8*)(ws + (size_t)((4 * w + m) * 4 + 2 + kt2) * 512 + l * 8);
#pragma unroll
      for (int nt = 0; nt < 2; ++nt) c0[m][nt] = MFMA16(af, bf[nt], c0[m][nt]);
    }
  }

  for (int n = 0; n < kSteps; ++n) {
    const float s = (float)n * kDs;

    // ================= layer 1 (x-part K=64, C-init = c0) =================
    {
      f32x4 acc[4][2];
#pragma unroll
      for (int m = 0; m < 4; ++m)
#pragma unroll
        for (int nt = 0; nt < 2; ++nt) acc[m][nt] = c0[m][nt];
#pragma unroll
      for (int kt = 0; kt < 2; ++kt) {
        f16x8 bf[2];
#pragma unroll
        for (int nt = 0; nt < 2; ++nt)
          bf[nt] = *(const f16x8*)&xB[16 * nt + lm][kt * 32 + lq * 8];
#pragma unroll
        for (int m = 0; m < 4; ++m) {
          const f16x8 af =
              *(const f16x8*)(ws + (size_t)((4 * w + m) * 4 + kt) * 512 + l * 8);
#pragma unroll
          for (int nt = 0; nt < 2; ++nt) acc[m][nt] = MFMA16(af, bf[nt], acc[m][nt]);
        }
      }
#pragma unroll
      for (int m = 0; m < 4; ++m) {
        const int nn = (4 * w + m) * 16 + 4 * lq;     // 4 consecutive neurons
        const float4 bb = *(const float4*)&sB[nn];
        const float4 sw = *(const float4*)&sB[256 + nn];
        f32x4 be;
        be[0] = fmaf(s, sw.x, bb.x); be[1] = fmaf(s, sw.y, bb.y);
        be[2] = fmaf(s, sw.z, bb.z); be[3] = fmaf(s, sw.w, bb.w);
#pragma unroll
        for (int nt = 0; nt < 2; ++nt) {
          f16x4 hv;
#pragma unroll
          for (int q = 0; q < 4; ++q)
            hv[q] = (_Float16)fmaxf(acc[m][nt][q] + be[q], 0.f);
          *(f16x4*)&h1[16 * nt + lm][nn] = hv;
        }
      }
    }
    __syncthreads();

    // ================= layer 2 (K=256) =================
    {
      f32x4 acc[4][2];
#pragma unroll
      for (int m = 0; m < 4; ++m) {
        const int nn = (4 * w + m) * 16 + 4 * lq;
        const float4 bb = *(const float4*)&sB[512 + nn];
        const f32x4 bi = {bb.x, bb.y, bb.z, bb.w};
#pragma unroll
        for (int nt = 0; nt < 2; ++nt) acc[m][nt] = bi;
      }
#pragma unroll
      for (int kt = 0; kt < 8; ++kt) {
        f16x8 bf[2];
#pragma unroll
        for (int nt = 0; nt < 2; ++nt)
          bf[nt] = *(const f16x8*)&h1[16 * nt + lm][kt * 32 + lq * 8];
#pragma unroll
        for (int m = 0; m < 4; ++m) {
          const f16x8 af =
              *(const f16x8*)(ws + (size_t)(64 + (4 * w + m) * 8 + kt) * 512 + l * 8);
#pragma unroll
          for (int nt = 0; nt < 2; ++nt) acc[m][nt] = MFMA16(af, bf[nt], acc[m][nt]);
        }
      }
#pragma unroll
      for (int m = 0; m < 4; ++m) {
        const int nn = (4 * w + m) * 16 + 4 * lq;
#pragma unroll
        for (int nt = 0; nt < 2; ++nt) {
          f16x4 hv;
#pragma unroll
          for (int q = 0; q < 4; ++q)
            hv[q] = (_Float16)fmaxf(acc[m][nt][q], 0.f);
          *(f16x4*)&h2[16 * nt + lm][nn] = hv;
        }
      }
    }
    __syncthreads();

    // ================= layer 3 (M=64; wave w -> M-tile w) =================
    {
      const int nn = w * 16 + 4 * lq;
      const float4 bb = *(const float4*)&sB[768 + nn];
      f32x4 a3[2];
      a3[0] = (f32x4){bb.x, bb.y, bb.z, bb.w};
      a3[1] = a3[0];
#pragma unroll
      for (int kt = 0; kt < 8; ++kt) {
        const f16x8 af =
            *(const f16x8*)(ws + (size_t)(192 + w * 8 + kt) * 512 + l * 8);
        const f16x8 bf0 = *(const f16x8*)&h2[lm][kt * 32 + lq * 8];
        const f16x8 bf1 = *(const f16x8*)&h2[16 + lm][kt * 32 + lq * 8];
        a3[0] = MFMA16(af, bf0, a3[0]);
        a3[1] = MFMA16(af, bf1, a3[1]);
      }
#pragma unroll
      for (int i = 0; i < 2; ++i)
        *(f32x4*)&drF[16 * i + lm][nn] = a3[i];
    }
    __syncthreads();

    // ================= Euler-Maruyama update =================
    {
      uint32_t ka, kb;
      if (n == 0) {
        ka = kd0; kb = kd1;
      } else {
        uint32_t na, nb2, xa, xb;
        jax_split(kl0, kl1, na, nb2, xa, xb);
        kl0 = na; kl1 = nb2; ka = xa; kb = xb;
      }
      const float sg   = 1.0f - s;
      const float A    = (n == 0) ? 0.0f : 1.0f / (s * sg);
      const float coef = 0.5f * (1.0f - sg * sg);

      const float4 da = *(const float4*)&drF[li][ci];
      const float4 db = *(const float4*)&drF[li][ci + 4];
      const float dv[8] = {da.x, da.y, da.z, da.w, db.x, db.y, db.z, db.w};
      f16x8 hx;
#pragma unroll
      for (int j = 0; j < 8; ++j) {
        const uint32_t gi = (uint32_t)((r0 + li) * kDim + ci + j);
        const float eta   = bits_to_normal(draw_bits(ka, kb, gi));
        const float score = A * (s * dv[j] - (X[j] - X0r[j]));
        X[j] = X[j] + kDs * (dv[j] + coef * score) + kSqrtDs * eta;
        hx[j] = (_Float16)X[j];
      }
      *(f16x8*)&xB[li][ci] = hx;
    }
    __syncthreads();
  }

  // ---- write result ----
  const size_t ob = (size_t)samp * ((size_t)kObs * kDim) +
                    (size_t)(r0 + li) * kDim + ci;
  *(float4*)(out + ob)     = make_float4(X[0], X[1], X[2], X[3]);
  *(float4*)(out + ob + 4) = make_float4(X[4], X[5], X[6], X[7]);
}

extern "C" void kernel_launch(void* const* d_in, const int* in_sizes, int n_in,
                              void* d_out, int out_size, void* d_ws, size_t ws_size,
                              hipStream_t stream) {
  const float* X0 = (const float*)d_in[0];
  const float* W1 = (const float*)d_in[1];
  const float* b1 = (const float*)d_in[2];
  const float* W2 = (const float*)d_in[3];
  const float* b2 = (const float*)d_in[4];
  const float* W3 = (const float*)d_in[5];
  const float* b3 = (const float*)d_in[6];
  _Float16* ws = (_Float16*)d_ws;   // 224 KB of A-operand fragments

  prep_weights<<<dim3(224), dim3(256), 0, stream>>>(W1, W2, W3, ws);
  sde_mfma5<<<dim3(4096), dim3(256), 0, stream>>>(X0, W1, b1, b2, b3, ws,
                                                  (float*)d_out);
}

// Round 6
// 6464.621 us; speedup vs baseline: 1.2431x; 1.2431x over previous
//
#include <hip/hip_runtime.h>
#include <stdint.h>

// ---------------------------------------------------------------------------
// Fused SDE sampler, round 6.
//   Diagnosis r3-r5: every config that squeezed the register budget below
//   the live set (launch_bounds(512,4), waves_per_eu(4), waves_per_eu(3,4))
//   spilled; the scratch working set thrashed the 4MB/XCD L2 and pushed the
//   weight-fragment stream to ~50% L2 miss (FETCH 14-22 GB). r2 (2 waves/EU,
//   256-reg budget, zero spills) remains fastest. This kernel wants
//   registers, not occupancy.
//   Round 6 = r5 lean structure + fat register budget:
//   - amdgpu_waves_per_eu(2): 256-reg unified cap -> no spills, deep
//     load pipelining for the W2 fragment stream.
//   - L1-x and L3 weight fragments register-cached once before the step
//     loop (64 VGPRs) -> per-step weight stream 192 -> 128 KB/block.
//   - Kept: swapped MFMA operands (A=weights), c0 = x0@W1[64:128] hoisted
//     into persistent accumulators, biases in LDS, f32 drift overlay,
//     bit-exact JAX threefry RNG (verified r1-r5).
// ---------------------------------------------------------------------------

#define PARTITIONABLE 1

namespace {

constexpr int   kObs    = 65536;
constexpr int   kDim    = 64;
constexpr int   kSteps  = 64;
constexpr float kDs     = 1.0f / 64.0f;
constexpr float kSqrtDs = 0.125f;

typedef _Float16 f16x8 __attribute__((ext_vector_type(8)));
typedef _Float16 f16x4 __attribute__((ext_vector_type(4)));
typedef float    f32x4 __attribute__((ext_vector_type(4)));

#define MFMA16(a, b, c) __builtin_amdgcn_mfma_f32_16x16x32_f16((a), (b), (c), 0, 0, 0)

__device__ __forceinline__ uint32_t rotl(uint32_t v, int r) {
  return (v << r) | (v >> (32 - r));
}

__device__ __forceinline__ void tf2x32(uint32_t k0, uint32_t k1,
                                       uint32_t& x0, uint32_t& x1) {
  uint32_t k2 = k0 ^ k1 ^ 0x1BD11BDAu;
  x0 += k0; x1 += k1;
  x0 += x1; x1 = rotl(x1, 13); x1 ^= x0;
  x0 += x1; x1 = rotl(x1, 15); x1 ^= x0;
  x0 += x1; x1 = rotl(x1, 26); x1 ^= x0;
  x0 += x1; x1 = rotl(x1,  6); x1 ^= x0;
  x0 += k1; x1 += k2 + 1u;
  x0 += x1; x1 = rotl(x1, 17); x1 ^= x0;
  x0 += x1; x1 = rotl(x1, 29); x1 ^= x0;
  x0 += x1; x1 = rotl(x1, 16); x1 ^= x0;
  x0 += x1; x1 = rotl(x1, 24); x1 ^= x0;
  x0 += k2; x1 += k0 + 2u;
  x0 += x1; x1 = rotl(x1, 13); x1 ^= x0;
  x0 += x1; x1 = rotl(x1, 15); x1 ^= x0;
  x0 += x1; x1 = rotl(x1, 26); x1 ^= x0;
  x0 += x1; x1 = rotl(x1,  6); x1 ^= x0;
  x0 += k0; x1 += k1 + 3u;
  x0 += x1; x1 = rotl(x1, 17); x1 ^= x0;
  x0 += x1; x1 = rotl(x1, 29); x1 ^= x0;
  x0 += x1; x1 = rotl(x1, 16); x1 ^= x0;
  x0 += x1; x1 = rotl(x1, 24); x1 ^= x0;
  x0 += k1; x1 += k2 + 4u;
  x0 += x1; x1 = rotl(x1, 13); x1 ^= x0;
  x0 += x1; x1 = rotl(x1, 15); x1 ^= x0;
  x0 += x1; x1 = rotl(x1, 26); x1 ^= x0;
  x0 += x1; x1 = rotl(x1,  6); x1 ^= x0;
  x0 += k2; x1 += k0 + 5u;
}

__device__ __forceinline__ void jax_split(uint32_t k0, uint32_t k1,
                                          uint32_t& a0, uint32_t& a1,
                                          uint32_t& b0, uint32_t& b1) {
#if PARTITIONABLE
  uint32_t x0 = 0u, x1 = 0u; tf2x32(k0, k1, x0, x1); a0 = x0; a1 = x1;
  uint32_t y0 = 0u, y1 = 1u; tf2x32(k0, k1, y0, y1); b0 = y0; b1 = y1;
#else
  uint32_t x0 = 0u, x1 = 2u; tf2x32(k0, k1, x0, x1);
  uint32_t y0 = 1u, y1 = 3u; tf2x32(k0, k1, y0, y1);
  a0 = x0; a1 = y0; b0 = x1; b1 = y1;
#endif
}

__device__ __forceinline__ uint32_t draw_bits(uint32_t k0, uint32_t k1, uint32_t i) {
#if PARTITIONABLE
  uint32_t x0 = 0u, x1 = i;
  tf2x32(k0, k1, x0, x1);
  return x0 ^ x1;
#else
  const uint32_t half = (uint32_t)kObs * kDim / 2;
  if (i < half) {
    uint32_t x0 = i, x1 = i + half; tf2x32(k0, k1, x0, x1); return x0;
  } else {
    uint32_t x0 = i - half, x1 = i; tf2x32(k0, k1, x0, x1); return x1;
  }
#endif
}

__device__ __forceinline__ float erfinv32(float x) {
  float w = -log1pf(-x * x);
  float p;
  if (w < 5.0f) {
    w = w - 2.5f;
    p =            2.81022636e-08f;
    p = fmaf(p, w, 3.43273939e-07f);
    p = fmaf(p, w, -3.5233877e-06f);
    p = fmaf(p, w, -4.39150654e-06f);
    p = fmaf(p, w, 0.00021858087f);
    p = fmaf(p, w, -0.00125372503f);
    p = fmaf(p, w, -0.00417768164f);
    p = fmaf(p, w, 0.246640727f);
    p = fmaf(p, w, 1.50140941f);
  } else {
    w = sqrtf(w) - 3.0f;
    p =            -0.000200214257f;
    p = fmaf(p, w, 0.000100950558f);
    p = fmaf(p, w, 0.00134934322f);
    p = fmaf(p, w, -0.00367342844f);
    p = fmaf(p, w, 0.00573950773f);
    p = fmaf(p, w, -0.0076224613f);
    p = fmaf(p, w, 0.00943887047f);
    p = fmaf(p, w, 1.00167406f);
    p = fmaf(p, w, 2.83297682f);
  }
  return p * x;
}

__device__ __forceinline__ float bits_to_normal(uint32_t bits) {
  const float lo = -0.99999994f;
  float f = __uint_as_float(0x3f800000u | (bits >> 9)) - 1.0f;
  float u = fmaxf(lo, fmaf(f, 2.0f, lo));
  return 1.41421356237f * erfinv32(u);
}

}  // namespace

// ---------------------------------------------------------------------------
// Weight prep (unchanged since r3): fp32 -> f16 MFMA A-operand fragments.
// Tile = 16(M=neuron) x 32(K) = 1024 B; lane l holds A[m=l&15][k=(l>>4)*8+j].
//   L1: tiles [  0, 64): id =       Mt*4 + kt  (kt 0,1 = x rows; 2,3 = x0)
//   L2: tiles [ 64,192): id =  64 + Mt*8 + kt
//   L3: tiles [192,224): id = 192 + Mt*8 + kt  (Mt 0..3)
// ---------------------------------------------------------------------------
__global__ void prep_weights(const float* __restrict__ W1,
                             const float* __restrict__ W2,
                             const float* __restrict__ W3,
                             _Float16* __restrict__ ws) {
  const int tile = blockIdx.x;
  const int t    = threadIdx.x;
  const int lane = t >> 2;
  const int j0   = (t & 3) * 2;
  const int lm   = lane & 15;
  const int hi   = lane >> 4;

  int Mt, kt, ld;
  const float* src;
  if (tile < 64)       { Mt = tile >> 2;            kt = tile & 3; src = W1; ld = 256; }
  else if (tile < 192) { int u = tile - 64;  Mt = u >> 3; kt = u & 7; src = W2; ld = 256; }
  else                 { int u = tile - 192; Mt = u >> 3; kt = u & 7; src = W3; ld = 64;  }

  const int col = Mt * 16 + lm;
#pragma unroll
  for (int jj = 0; jj < 2; ++jj) {
    const int j = j0 + jj;
    const int k = kt * 32 + hi * 8 + j;
    ws[(size_t)tile * 512 + lane * 8 + j] = (_Float16)src[k * ld + col];
  }
}

// ---------------------------------------------------------------------------
// Main fused kernel: 32 rows/block, 256 threads (4 waves).
// Wave w owns M-tiles {4w..4w+3} (neurons 64w..64w+64) for L1/L2, both
// N-tiles; for L3 (M=64) wave w owns M-tile w, both N-tiles.
// ---------------------------------------------------------------------------
__global__ __launch_bounds__(256)
__attribute__((amdgpu_waves_per_eu(2)))
void sde_mfma6(const float* __restrict__ X0g,
               const float* __restrict__ W1,
               const float* __restrict__ b1g,
               const float* __restrict__ b2g,
               const float* __restrict__ b3g,
               const _Float16* __restrict__ ws,
               float* __restrict__ out) {
  // LDS: 4608 + 16896 + 16896 + 3328 = 41728 B (reg-limited to 2 blocks/CU).
  __shared__ alignas(16) _Float16 xB[32][72];    // X as f16, B-frag layout
  __shared__ alignas(16) _Float16 h1[32][264];
  __shared__ alignas(16) _Float16 h2[32][264];
  __shared__ alignas(16) float    sB[832];       // b1|w1s|b2|b3
  // f32 drift overlay on h1 (dead there by L3): 32*72*4 = 9216 <= 16896
  float (*drF)[72] = reinterpret_cast<float (*)[72]>(&h1[0][0]);

  const int t  = threadIdx.x;
  const int w  = t >> 6;                 // wave 0..3
  const int l  = t & 63;
  const int lq = l >> 4;                 // quad
  const int lm = l & 15;
  const int samp = blockIdx.x >> 11;     // 2048 blocks per sample chain
  const int tile = blockIdx.x & 2047;
  const int r0   = tile * 32;

  const int li = t >> 3;                 // update-phase row 0..31
  const int ci = (t & 7) * 8;            // update-phase col base

  // ---- init: X/X0 in registers, xB <- f16(X0), biases -> LDS ----
  float X[8], X0r[8];
  {
    const float* p = X0g + (size_t)(r0 + li) * kDim + ci;
    const float4 a = *(const float4*)p;
    const float4 b = *(const float4*)(p + 4);
    X0r[0] = a.x; X0r[1] = a.y; X0r[2] = a.z; X0r[3] = a.w;
    X0r[4] = b.x; X0r[5] = b.y; X0r[6] = b.z; X0r[7] = b.w;
    f16x8 hx;
#pragma unroll
    for (int j = 0; j < 8; ++j) { X[j] = X0r[j]; hx[j] = (_Float16)X0r[j]; }
    *(f16x8*)&xB[li][ci] = hx;
  }
  {
    sB[t]       = b1g[t];
    sB[256 + t] = W1[128 * 256 + t];
    sB[512 + t] = b2g[t];
    if (t < 64) sB[768 + t] = b3g[t];
  }

  // ---- register-cached weight fragments (loop-invariant) ----
  // L1 x-part: 8 frags = 32 VGPRs; L3: 8 frags = 32 VGPRs.
  f16x8 wL1[2][4];
#pragma unroll
  for (int kt = 0; kt < 2; ++kt)
#pragma unroll
    for (int m = 0; m < 4; ++m)
      wL1[kt][m] =
          *(const f16x8*)(ws + (size_t)((4 * w + m) * 4 + kt) * 512 + l * 8);
  f16x8 wL3[8];
#pragma unroll
  for (int kt = 0; kt < 8; ++kt)
    wL3[kt] = *(const f16x8*)(ws + (size_t)(192 + w * 8 + kt) * 512 + l * 8);

  // ---- RNG key chain ----
  uint32_t s0a, s0b, s1a, s1b;
  jax_split(0u, 1u, s0a, s0b, s1a, s1b);
  const uint32_t sk0 = samp ? s1a : s0a;
  const uint32_t sk1 = samp ? s1b : s0b;
  uint32_t kd0, kd1, kl0, kl1;
  jax_split(sk0, sk1, kd0, kd1, kl0, kl1);

  __syncthreads();

  // ---- c0[m][nt] = x0 @ W1[64:128]  (persistent accumulator C-init) ----
  f32x4 c0[4][2];
#pragma unroll
  for (int m = 0; m < 4; ++m)
#pragma unroll
    for (int nt = 0; nt < 2; ++nt) c0[m][nt] = (f32x4){0.f, 0.f, 0.f, 0.f};
#pragma unroll
  for (int kt2 = 0; kt2 < 2; ++kt2) {
    f16x8 bf[2];
#pragma unroll
    for (int nt = 0; nt < 2; ++nt)
      bf[nt] = *(const f16x8*)&xB[16 * nt + lm][kt2 * 32 + lq * 8];  // xB==x0
#pragma unroll
    for (int m = 0; m < 4; ++m) {
      const f16x8 af =
          *(const f16x8*)(ws + (size_t)((4 * w + m) * 4 + 2 + kt2) * 512 + l * 8);
#pragma unroll
      for (int nt = 0; nt < 2; ++nt) c0[m][nt] = MFMA16(af, bf[nt], c0[m][nt]);
    }
  }

  for (int n = 0; n < kSteps; ++n) {
    const float s = (float)n * kDs;

    // ================= layer 1 (x-part K=64, C-init = c0) =================
    {
      f32x4 acc[4][2];
#pragma unroll
      for (int m = 0; m < 4; ++m)
#pragma unroll
        for (int nt = 0; nt < 2; ++nt) acc[m][nt] = c0[m][nt];
#pragma unroll
      for (int kt = 0; kt < 2; ++kt) {
        f16x8 bf[2];
#pragma unroll
        for (int nt = 0; nt < 2; ++nt)
          bf[nt] = *(const f16x8*)&xB[16 * nt + lm][kt * 32 + lq * 8];
#pragma unroll
        for (int m = 0; m < 4; ++m)
#pragma unroll
          for (int nt = 0; nt < 2; ++nt)
            acc[m][nt] = MFMA16(wL1[kt][m], bf[nt], acc[m][nt]);
      }
#pragma unroll
      for (int m = 0; m < 4; ++m) {
        const int nn = (4 * w + m) * 16 + 4 * lq;     // 4 consecutive neurons
        const float4 bb = *(const float4*)&sB[nn];
        const float4 sw = *(const float4*)&sB[256 + nn];
        f32x4 be;
        be[0] = fmaf(s, sw.x, bb.x); be[1] = fmaf(s, sw.y, bb.y);
        be[2] = fmaf(s, sw.z, bb.z); be[3] = fmaf(s, sw.w, bb.w);
#pragma unroll
        for (int nt = 0; nt < 2; ++nt) {
          f16x4 hv;
#pragma unroll
          for (int q = 0; q < 4; ++q)
            hv[q] = (_Float16)fmaxf(acc[m][nt][q] + be[q], 0.f);
          *(f16x4*)&h1[16 * nt + lm][nn] = hv;
        }
      }
    }
    __syncthreads();

    // ================= layer 2 (K=256, W2 streams from L2) =================
    {
      f32x4 acc[4][2];
#pragma unroll
      for (int m = 0; m < 4; ++m) {
        const int nn = (4 * w + m) * 16 + 4 * lq;
        const float4 bb = *(const float4*)&sB[512 + nn];
        const f32x4 bi = {bb.x, bb.y, bb.z, bb.w};
#pragma unroll
        for (int nt = 0; nt < 2; ++nt) acc[m][nt] = bi;
      }
#pragma unroll
      for (int kt = 0; kt < 8; ++kt) {
        f16x8 bf[2];
#pragma unroll
        for (int nt = 0; nt < 2; ++nt)
          bf[nt] = *(const f16x8*)&h1[16 * nt + lm][kt * 32 + lq * 8];
#pragma unroll
        for (int m = 0; m < 4; ++m) {
          const f16x8 af =
              *(const f16x8*)(ws + (size_t)(64 + (4 * w + m) * 8 + kt) * 512 + l * 8);
#pragma unroll
          for (int nt = 0; nt < 2; ++nt) acc[m][nt] = MFMA16(af, bf[nt], acc[m][nt]);
        }
      }
#pragma unroll
      for (int m = 0; m < 4; ++m) {
        const int nn = (4 * w + m) * 16 + 4 * lq;
#pragma unroll
        for (int nt = 0; nt < 2; ++nt) {
          f16x4 hv;
#pragma unroll
          for (int q = 0; q < 4; ++q)
            hv[q] = (_Float16)fmaxf(acc[m][nt][q], 0.f);
          *(f16x4*)&h2[16 * nt + lm][nn] = hv;
        }
      }
    }
    __syncthreads();

    // ================= layer 3 (M=64; wave w -> M-tile w) =================
    {
      const int nn = w * 16 + 4 * lq;
      const float4 bb = *(const float4*)&sB[768 + nn];
      f32x4 a3[2];
      a3[0] = (f32x4){bb.x, bb.y, bb.z, bb.w};
      a3[1] = a3[0];
#pragma unroll
      for (int kt = 0; kt < 8; ++kt) {
        const f16x8 bf0 = *(const f16x8*)&h2[lm][kt * 32 + lq * 8];
        const f16x8 bf1 = *(const f16x8*)&h2[16 + lm][kt * 32 + lq * 8];
        a3[0] = MFMA16(wL3[kt], bf0, a3[0]);
        a3[1] = MFMA16(wL3[kt], bf1, a3[1]);
      }
#pragma unroll
      for (int i = 0; i < 2; ++i)
        *(f32x4*)&drF[16 * i + lm][nn] = a3[i];
    }
    __syncthreads();

    // ================= Euler-Maruyama update =================
    {
      uint32_t ka, kb;
      if (n == 0) {
        ka = kd0; kb = kd1;
      } else {
        uint32_t na, nb2, xa, xb;
        jax_split(kl0, kl1, na, nb2, xa, xb);
        kl0 = na; kl1 = nb2; ka = xa; kb = xb;
      }
      const float sg   = 1.0f - s;
      const float A    = (n == 0) ? 0.0f : 1.0f / (s * sg);
      const float coef = 0.5f * (1.0f - sg * sg);

      const float4 da = *(const float4*)&drF[li][ci];
      const float4 db = *(const float4*)&drF[li][ci + 4];
      const float dv[8] = {da.x, da.y, da.z, da.w, db.x, db.y, db.z, db.w};
      f16x8 hx;
#pragma unroll
      for (int j = 0; j < 8; ++j) {
        const uint32_t gi = (uint32_t)((r0 + li) * kDim + ci + j);
        const float eta   = bits_to_normal(draw_bits(ka, kb, gi));
        const float score = A * (s * dv[j] - (X[j] - X0r[j]));
        X[j] = X[j] + kDs * (dv[j] + coef * score) + kSqrtDs * eta;
        hx[j] = (_Float16)X[j];
      }
      *(f16x8*)&xB[li][ci] = hx;
    }
    __syncthreads();
  }

  // ---- write result ----
  const size_t ob = (size_t)samp * ((size_t)kObs * kDim) +
                    (size_t)(r0 + li) * kDim + ci;
  *(float4*)(out + ob)     = make_float4(X[0], X[1], X[2], X[3]);
  *(float4*)(out + ob + 4) = make_float4(X[4], X[5], X[6], X[7]);
}

extern "C" void kernel_launch(void* const* d_in, const int* in_sizes, int n_in,
                              void* d_out, int out_size, void* d_ws, size_t ws_size,
                              hipStream_t stream) {
  const float* X0 = (const float*)d_in[0];
  const float* W1 = (const float*)d_in[1];
  const float* b1 = (const float*)d_in[2];
  const float* W2 = (const float*)d_in[3];
  const float* b2 = (const float*)d_in[4];
  const float* W3 = (const float*)d_in[5];
  const float* b3 = (const float*)d_in[6];
  _Float16* ws = (_Float16*)d_ws;   // 224 KB of A-operand fragments

  prep_weights<<<dim3(224), dim3(256), 0, stream>>>(W1, W2, W3, ws);
  sde_mfma6<<<dim3(4096), dim3(256), 0, stream>>>(X0, W1, b1, b2, b3, ws,
                                                  (float*)d_out);
}

// Round 7
// 5852.822 us; speedup vs baseline: 1.3731x; 1.1045x over previous
//
#include <hip/hip_runtime.h>
#include <stdint.h>

// ---------------------------------------------------------------------------
// Fused SDE sampler, round 7.
//   r2-r6 diagnosis: WRITE_SIZE 11x output + FETCH 25x scratch-writes =>
//   long-lived registers spilled once and re-read EVERY step at HBM latency.
//   Compiler caps arch VGPRs at 128 regardless of waves_per_eu. Fix: shrink
//   the live set below 128 so spilling is impossible:
//   - No weight register caching, no c0 hoist (weights are L2-resident;
//     224 KB shared by all blocks in a 4 MB L2).
//   - L1 runs K=128 (x | x0) with x0 as a second LDS f16 operand region.
//   - X, X0 kept in registers in MFMA C-layout -> L3 accumulators feed the
//     Euler update directly in-register: no drift LDS round-trip, and only
//     3 barriers/step instead of 4.
//   - Biases folded into MFMA C-init.
//   - RNG bit-exact JAX threefry (verified r1-r6).
// ---------------------------------------------------------------------------

#define PARTITIONABLE 1

namespace {

constexpr int   kObs    = 65536;
constexpr int   kDim    = 64;
constexpr int   kSteps  = 64;
constexpr float kDs     = 1.0f / 64.0f;
constexpr float kSqrtDs = 0.125f;

typedef _Float16 f16x8 __attribute__((ext_vector_type(8)));
typedef _Float16 f16x4 __attribute__((ext_vector_type(4)));
typedef float    f32x4 __attribute__((ext_vector_type(4)));

#define MFMA16(a, b, c) __builtin_amdgcn_mfma_f32_16x16x32_f16((a), (b), (c), 0, 0, 0)

__device__ __forceinline__ uint32_t rotl(uint32_t v, int r) {
  return (v << r) | (v >> (32 - r));
}

__device__ __forceinline__ void tf2x32(uint32_t k0, uint32_t k1,
                                       uint32_t& x0, uint32_t& x1) {
  uint32_t k2 = k0 ^ k1 ^ 0x1BD11BDAu;
  x0 += k0; x1 += k1;
  x0 += x1; x1 = rotl(x1, 13); x1 ^= x0;
  x0 += x1; x1 = rotl(x1, 15); x1 ^= x0;
  x0 += x1; x1 = rotl(x1, 26); x1 ^= x0;
  x0 += x1; x1 = rotl(x1,  6); x1 ^= x0;
  x0 += k1; x1 += k2 + 1u;
  x0 += x1; x1 = rotl(x1, 17); x1 ^= x0;
  x0 += x1; x1 = rotl(x1, 29); x1 ^= x0;
  x0 += x1; x1 = rotl(x1, 16); x1 ^= x0;
  x0 += x1; x1 = rotl(x1, 24); x1 ^= x0;
  x0 += k2; x1 += k0 + 2u;
  x0 += x1; x1 = rotl(x1, 13); x1 ^= x0;
  x0 += x1; x1 = rotl(x1, 15); x1 ^= x0;
  x0 += x1; x1 = rotl(x1, 26); x1 ^= x0;
  x0 += x1; x1 = rotl(x1,  6); x1 ^= x0;
  x0 += k0; x1 += k1 + 3u;
  x0 += x1; x1 = rotl(x1, 17); x1 ^= x0;
  x0 += x1; x1 = rotl(x1, 29); x1 ^= x0;
  x0 += x1; x1 = rotl(x1, 16); x1 ^= x0;
  x0 += x1; x1 = rotl(x1, 24); x1 ^= x0;
  x0 += k1; x1 += k2 + 4u;
  x0 += x1; x1 = rotl(x1, 13); x1 ^= x0;
  x0 += x1; x1 = rotl(x1, 15); x1 ^= x0;
  x0 += x1; x1 = rotl(x1, 26); x1 ^= x0;
  x0 += x1; x1 = rotl(x1,  6); x1 ^= x0;
  x0 += k2; x1 += k0 + 5u;
}

__device__ __forceinline__ void jax_split(uint32_t k0, uint32_t k1,
                                          uint32_t& a0, uint32_t& a1,
                                          uint32_t& b0, uint32_t& b1) {
#if PARTITIONABLE
  uint32_t x0 = 0u, x1 = 0u; tf2x32(k0, k1, x0, x1); a0 = x0; a1 = x1;
  uint32_t y0 = 0u, y1 = 1u; tf2x32(k0, k1, y0, y1); b0 = y0; b1 = y1;
#else
  uint32_t x0 = 0u, x1 = 2u; tf2x32(k0, k1, x0, x1);
  uint32_t y0 = 1u, y1 = 3u; tf2x32(k0, k1, y0, y1);
  a0 = x0; a1 = y0; b0 = x1; b1 = y1;
#endif
}

__device__ __forceinline__ uint32_t draw_bits(uint32_t k0, uint32_t k1, uint32_t i) {
#if PARTITIONABLE
  uint32_t x0 = 0u, x1 = i;
  tf2x32(k0, k1, x0, x1);
  return x0 ^ x1;
#else
  const uint32_t half = (uint32_t)kObs * kDim / 2;
  if (i < half) {
    uint32_t x0 = i, x1 = i + half; tf2x32(k0, k1, x0, x1); return x0;
  } else {
    uint32_t x0 = i - half, x1 = i; tf2x32(k0, k1, x0, x1); return x1;
  }
#endif
}

__device__ __forceinline__ float erfinv32(float x) {
  float w = -log1pf(-x * x);
  float p;
  if (w < 5.0f) {
    w = w - 2.5f;
    p =            2.81022636e-08f;
    p = fmaf(p, w, 3.43273939e-07f);
    p = fmaf(p, w, -3.5233877e-06f);
    p = fmaf(p, w, -4.39150654e-06f);
    p = fmaf(p, w, 0.00021858087f);
    p = fmaf(p, w, -0.00125372503f);
    p = fmaf(p, w, -0.00417768164f);
    p = fmaf(p, w, 0.246640727f);
    p = fmaf(p, w, 1.50140941f);
  } else {
    w = sqrtf(w) - 3.0f;
    p =            -0.000200214257f;
    p = fmaf(p, w, 0.000100950558f);
    p = fmaf(p, w, 0.00134934322f);
    p = fmaf(p, w, -0.00367342844f);
    p = fmaf(p, w, 0.00573950773f);
    p = fmaf(p, w, -0.0076224613f);
    p = fmaf(p, w, 0.00943887047f);
    p = fmaf(p, w, 1.00167406f);
    p = fmaf(p, w, 2.83297682f);
  }
  return p * x;
}

__device__ __forceinline__ float bits_to_normal(uint32_t bits) {
  const float lo = -0.99999994f;
  float f = __uint_as_float(0x3f800000u | (bits >> 9)) - 1.0f;
  float u = fmaxf(lo, fmaf(f, 2.0f, lo));
  return 1.41421356237f * erfinv32(u);
}

}  // namespace

// ---------------------------------------------------------------------------
// Weight prep (unchanged since r3): fp32 -> f16 MFMA A-operand fragments.
// Tile = 16(M=neuron) x 32(K) = 1024 B; lane l holds A[m=l&15][k=(l>>4)*8+j].
//   L1: tiles [  0, 64): id =       Mt*4 + kt  (kt 0,1 = x rows; 2,3 = x0)
//   L2: tiles [ 64,192): id =  64 + Mt*8 + kt
//   L3: tiles [192,224): id = 192 + Mt*8 + kt  (Mt 0..3)
// ---------------------------------------------------------------------------
__global__ void prep_weights(const float* __restrict__ W1,
                             const float* __restrict__ W2,
                             const float* __restrict__ W3,
                             _Float16* __restrict__ ws) {
  const int tile = blockIdx.x;
  const int t    = threadIdx.x;
  const int lane = t >> 2;
  const int j0   = (t & 3) * 2;
  const int lm   = lane & 15;
  const int hi   = lane >> 4;

  int Mt, kt, ld;
  const float* src;
  if (tile < 64)       { Mt = tile >> 2;            kt = tile & 3; src = W1; ld = 256; }
  else if (tile < 192) { int u = tile - 64;  Mt = u >> 3; kt = u & 7; src = W2; ld = 256; }
  else                 { int u = tile - 192; Mt = u >> 3; kt = u & 7; src = W3; ld = 64;  }

  const int col = Mt * 16 + lm;
#pragma unroll
  for (int jj = 0; jj < 2; ++jj) {
    const int j = j0 + jj;
    const int k = kt * 32 + hi * 8 + j;
    ws[(size_t)tile * 512 + lane * 8 + j] = (_Float16)src[k * ld + col];
  }
}

// ---------------------------------------------------------------------------
// Main fused kernel: 32 rows/block, 256 threads (4 waves).
// Wave w owns M-tiles {4w..4w+3} (neurons 64w..64w+64) for L1/L2, both
// N-tiles; for L3 (M=64) wave w owns M-tile w (neurons 16w..16w+16), both
// N-tiles -> its accumulators cover X columns w*16+4lq..+3 at rows lm,16+lm,
// which is exactly the per-lane X register layout.
// ---------------------------------------------------------------------------
__global__ __launch_bounds__(256)
__attribute__((amdgpu_waves_per_eu(2)))
void sde_mfma7(const float* __restrict__ X0g,
               const float* __restrict__ W1,
               const float* __restrict__ b1g,
               const float* __restrict__ b2g,
               const float* __restrict__ b3g,
               const _Float16* __restrict__ ws,
               float* __restrict__ out) {
  // LDS: 4608*2 + 16896*2 + 3328 = 46336 B -> up to 3 blocks/CU.
  __shared__ alignas(16) _Float16 xB [32][72];   // X  (f16, row-major)
  __shared__ alignas(16) _Float16 x0B[32][72];   // X0 (f16, row-major)
  __shared__ alignas(16) _Float16 h1 [32][264];
  __shared__ alignas(16) _Float16 h2 [32][264];
  __shared__ alignas(16) float    sB[832];       // b1|w1s|b2|b3

  const int t  = threadIdx.x;
  const int w  = t >> 6;                 // wave 0..3
  const int l  = t & 63;
  const int lq = l >> 4;                 // quad
  const int lm = l & 15;
  const int samp = blockIdx.x >> 11;     // 2048 blocks per sample chain
  const int tile = blockIdx.x & 2047;
  const int r0   = tile * 32;

  const int cX = w * 16 + 4 * lq;        // this lane's X column base (C-layout)

  // ---- init: X/X0 registers in C-layout; xB/x0B <- f16(X0); biases->LDS ----
  float X[2][4], X0r[2][4];
#pragma unroll
  for (int i = 0; i < 2; ++i) {
    const int row = 16 * i + lm;
    const float4 v = *(const float4*)(X0g + (size_t)(r0 + row) * kDim + cX);
    X0r[i][0] = v.x; X0r[i][1] = v.y; X0r[i][2] = v.z; X0r[i][3] = v.w;
    f16x4 hv;
#pragma unroll
    for (int q = 0; q < 4; ++q) { X[i][q] = X0r[i][q]; hv[q] = (_Float16)X0r[i][q]; }
    *(f16x4*)&xB [row][cX] = hv;
    *(f16x4*)&x0B[row][cX] = hv;
  }
  {
    sB[t]       = b1g[t];
    sB[256 + t] = W1[128 * 256 + t];
    sB[512 + t] = b2g[t];
    if (t < 64) sB[768 + t] = b3g[t];
  }

  // ---- RNG key chain ----
  uint32_t s0a, s0b, s1a, s1b;
  jax_split(0u, 1u, s0a, s0b, s1a, s1b);
  const uint32_t sk0 = samp ? s1a : s0a;
  const uint32_t sk1 = samp ? s1b : s0b;
  uint32_t kd0, kd1, kl0, kl1;
  jax_split(sk0, sk1, kd0, kd1, kl0, kl1);

  for (int n = 0; n < kSteps; ++n) {
    const float s = (float)n * kDs;
    __syncthreads();   // xB writes (update / init) -> L1 reads

    // ========== layer 1: K=128 over (x | x0), bias+s*w1s in C-init ==========
    {
      f32x4 acc[4][2];
#pragma unroll
      for (int m = 0; m < 4; ++m) {
        const int nn = (4 * w + m) * 16 + 4 * lq;
        const float4 bb = *(const float4*)&sB[nn];
        const float4 sw = *(const float4*)&sB[256 + nn];
        f32x4 be;
        be[0] = fmaf(s, sw.x, bb.x); be[1] = fmaf(s, sw.y, bb.y);
        be[2] = fmaf(s, sw.z, bb.z); be[3] = fmaf(s, sw.w, bb.w);
        acc[m][0] = be; acc[m][1] = be;
      }
#pragma unroll
      for (int kt = 0; kt < 4; ++kt) {
        const _Float16* srcA = (kt < 2) ? &xB[0][0] : &x0B[0][0];
        const int ko = (kt & 1) * 32 + lq * 8;
        f16x8 bf[2];
#pragma unroll
        for (int nt = 0; nt < 2; ++nt)
          bf[nt] = *(const f16x8*)(srcA + (16 * nt + lm) * 72 + ko);
#pragma unroll
        for (int m = 0; m < 4; ++m) {
          const f16x8 af =
              *(const f16x8*)(ws + (size_t)((4 * w + m) * 4 + kt) * 512 + l * 8);
#pragma unroll
          for (int nt = 0; nt < 2; ++nt) acc[m][nt] = MFMA16(af, bf[nt], acc[m][nt]);
        }
      }
#pragma unroll
      for (int m = 0; m < 4; ++m) {
        const int nn = (4 * w + m) * 16 + 4 * lq;
#pragma unroll
        for (int nt = 0; nt < 2; ++nt) {
          f16x4 hv;
#pragma unroll
          for (int q = 0; q < 4; ++q)
            hv[q] = (_Float16)fmaxf(acc[m][nt][q], 0.f);
          *(f16x4*)&h1[16 * nt + lm][nn] = hv;
        }
      }
    }
    __syncthreads();

    // ================= layer 2 (K=256, W2 streams from L2) =================
    {
      f32x4 acc[4][2];
#pragma unroll
      for (int m = 0; m < 4; ++m) {
        const int nn = (4 * w + m) * 16 + 4 * lq;
        const float4 bb = *(const float4*)&sB[512 + nn];
        const f32x4 bi = {bb.x, bb.y, bb.z, bb.w};
        acc[m][0] = bi; acc[m][1] = bi;
      }
#pragma unroll
      for (int kt = 0; kt < 8; ++kt) {
        f16x8 bf[2];
#pragma unroll
        for (int nt = 0; nt < 2; ++nt)
          bf[nt] = *(const f16x8*)&h1[16 * nt + lm][kt * 32 + lq * 8];
#pragma unroll
        for (int m = 0; m < 4; ++m) {
          const f16x8 af =
              *(const f16x8*)(ws + (size_t)(64 + (4 * w + m) * 8 + kt) * 512 + l * 8);
#pragma unroll
          for (int nt = 0; nt < 2; ++nt) acc[m][nt] = MFMA16(af, bf[nt], acc[m][nt]);
        }
      }
#pragma unroll
      for (int m = 0; m < 4; ++m) {
        const int nn = (4 * w + m) * 16 + 4 * lq;
#pragma unroll
        for (int nt = 0; nt < 2; ++nt) {
          f16x4 hv;
#pragma unroll
          for (int q = 0; q < 4; ++q)
            hv[q] = (_Float16)fmaxf(acc[m][nt][q], 0.f);
          *(f16x4*)&h2[16 * nt + lm][nn] = hv;
        }
      }
    }
    __syncthreads();

    // ===== layer 3 (M=64; wave w -> M-tile w) + in-register update =====
    {
      const float4 bb = *(const float4*)&sB[768 + cX];
      f32x4 a3[2];
      a3[0] = (f32x4){bb.x, bb.y, bb.z, bb.w};
      a3[1] = a3[0];
#pragma unroll
      for (int kt = 0; kt < 8; ++kt) {
        const f16x8 af =
            *(const f16x8*)(ws + (size_t)(192 + w * 8 + kt) * 512 + l * 8);
        const f16x8 bf0 = *(const f16x8*)&h2[lm][kt * 32 + lq * 8];
        const f16x8 bf1 = *(const f16x8*)&h2[16 + lm][kt * 32 + lq * 8];
        a3[0] = MFMA16(af, bf0, a3[0]);
        a3[1] = MFMA16(af, bf1, a3[1]);
      }

      // per-step key
      uint32_t ka, kb;
      if (n == 0) {
        ka = kd0; kb = kd1;
      } else {
        uint32_t na, nb2, xa, xb;
        jax_split(kl0, kl1, na, nb2, xa, xb);
        kl0 = na; kl1 = nb2; ka = xa; kb = xb;
      }
      const float sg   = 1.0f - s;
      const float A    = (n == 0) ? 0.0f : 1.0f / (s * sg);
      const float coef = 0.5f * (1.0f - sg * sg);

#pragma unroll
      for (int i = 0; i < 2; ++i) {
        const int row = 16 * i + lm;
        const uint32_t gbase = (uint32_t)((r0 + row) * kDim + cX);
        f16x4 hv;
#pragma unroll
        for (int q = 0; q < 4; ++q) {
          const float eta   = bits_to_normal(draw_bits(ka, kb, gbase + q));
          const float dv    = a3[i][q];
          const float score = A * (s * dv - (X[i][q] - X0r[i][q]));
          X[i][q] = X[i][q] + kDs * (dv + coef * score) + kSqrtDs * eta;
          hv[q] = (_Float16)X[i][q];
        }
        *(f16x4*)&xB[row][cX] = hv;   // ordered before next L1 by loop-top bar
      }
    }
  }

  // ---- write result (C-layout) ----
#pragma unroll
  for (int i = 0; i < 2; ++i) {
    const size_t ob = (size_t)samp * ((size_t)kObs * kDim) +
                      (size_t)(r0 + 16 * i + lm) * kDim + cX;
    *(float4*)(out + ob) = make_float4(X[i][0], X[i][1], X[i][2], X[i][3]);
  }
}

extern "C" void kernel_launch(void* const* d_in, const int* in_sizes, int n_in,
                              void* d_out, int out_size, void* d_ws, size_t ws_size,
                              hipStream_t stream) {
  const float* X0 = (const float*)d_in[0];
  const float* W1 = (const float*)d_in[1];
  const float* b1 = (const float*)d_in[2];
  const float* W2 = (const float*)d_in[3];
  const float* b2 = (const float*)d_in[4];
  const float* W3 = (const float*)d_in[5];
  const float* b3 = (const float*)d_in[6];
  _Float16* ws = (_Float16*)d_ws;   // 224 KB of A-operand fragments

  prep_weights<<<dim3(224), dim3(256), 0, stream>>>(W1, W2, W3, ws);
  sde_mfma7<<<dim3(4096), dim3(256), 0, stream>>>(X0, W1, b1, b2, b3, ws,
                                                  (float*)d_out);
}